// Round 1
// baseline (709.616 us; speedup 1.0000x reference)
//
#include <hip/hip_runtime.h>
#include <hip/hip_bf16.h>

#define B_   32
#define L_   1024
#define DIN  256
#define EMB_ 128

// ---------------------------------------------------------------------------
// Kernel 1: fold Wc = W_eg @ Wg  [256x128],  bc = b_eg @ Wg  [128]
// ---------------------------------------------------------------------------
__global__ __launch_bounds__(256) void k_fold(
    const float* __restrict__ W_eg, const float* __restrict__ b_eg,
    const float* __restrict__ Wg, float* __restrict__ Wc, float* __restrict__ bc) {
  int idx = blockIdx.x * 256 + threadIdx.x;
  if (idx < DIN * EMB_) {
    int d = idx >> 7, o = idx & 127;
    float s = 0.f;
    for (int k = 0; k < EMB_; ++k) s += W_eg[d * EMB_ + k] * Wg[k * EMB_ + o];
    Wc[idx] = s;
  } else if (idx < DIN * EMB_ + EMB_) {
    int o = idx - DIN * EMB_;
    float s = 0.f;
    for (int k = 0; k < EMB_; ++k) s += b_eg[k] * Wg[k * EMB_ + o];
    bc[o] = s;
  }
}

// ---------------------------------------------------------------------------
// Kernel 2: EA = traj@W_ge + b_ge ; TH(theta) = traj@Wc + bc  (all B*L rows)
// Tiled fp32 GEMM: block = 32 rows x 256 cols (cols 0-127 -> EA, 128-255 -> TH)
// thread micro-tile 4 rows x 8 cols, K staged in chunks of 32.
// ---------------------------------------------------------------------------
__global__ __launch_bounds__(256) void k_embed(
    const float* __restrict__ traj,
    const float* __restrict__ W_ge, const float* __restrict__ b_ge,
    const float* __restrict__ Wc,   const float* __restrict__ bc,
    float* __restrict__ EA, float* __restrict__ TH) {
  __shared__ float Tt[32][36];    // transposed traj chunk: Tt[k][row]
  __shared__ float Wl[32][256];   // weight chunk: Wl[k][col]
  const int tid = threadIdx.x;
  const int R0  = blockIdx.x * 32;
  const int r0  = (tid >> 5) * 4;   // 4 rows per thread
  const int c0  = (tid & 31) * 8;   // 8 cols per thread (never straddles 128)

  float acc[4][8];
#pragma unroll
  for (int r = 0; r < 4; ++r)
#pragma unroll
    for (int c = 0; c < 8; ++c) acc[r][c] = 0.f;

  for (int kc = 0; kc < DIN; kc += 32) {
    __syncthreads();
    // stage weights: 32x256 floats, 8 float4 per thread, coalesced
#pragma unroll
    for (int i = 0; i < 8; ++i) {
      int f4 = tid + i * 256;
      int w  = f4 * 4;
      int k  = w >> 8, cc = w & 255;
      float4 v;
      if (cc < 128) v = *(const float4*)&W_ge[(kc + k) * EMB_ + cc];
      else          v = *(const float4*)&Wc[(kc + k) * EMB_ + (cc - 128)];
      *(float4*)&Wl[k][cc] = v;
    }
    // stage traj transposed
    {
      int r = tid >> 3, kq = (tid & 7) * 4;
      float4 v = *(const float4*)&traj[(size_t)(R0 + r) * DIN + kc + kq];
      Tt[kq + 0][r] = v.x; Tt[kq + 1][r] = v.y;
      Tt[kq + 2][r] = v.z; Tt[kq + 3][r] = v.w;
    }
    __syncthreads();
#pragma unroll
    for (int k = 0; k < 32; ++k) {
      float4 a  = *(const float4*)&Tt[k][r0];
      float4 w0 = *(const float4*)&Wl[k][c0];
      float4 w1 = *(const float4*)&Wl[k][c0 + 4];
      float av[4] = {a.x, a.y, a.z, a.w};
      float wv[8] = {w0.x, w0.y, w0.z, w0.w, w1.x, w1.y, w1.z, w1.w};
#pragma unroll
      for (int r = 0; r < 4; ++r)
#pragma unroll
        for (int c = 0; c < 8; ++c) acc[r][c] += av[r] * wv[c];
    }
  }
  // epilogue: add bias, write out
  const float* bias = (c0 < 128) ? b_ge : bc;
  float*       dst  = (c0 < 128) ? EA   : TH;
  const int cc = c0 & 127;
  float bv[8];
#pragma unroll
  for (int c = 0; c < 8; ++c) bv[c] = bias[cc + c];
#pragma unroll
  for (int r = 0; r < 4; ++r) {
    size_t row = (size_t)(R0 + r0 + r);
    float4 o0 = make_float4(acc[r][0] + bv[0], acc[r][1] + bv[1],
                            acc[r][2] + bv[2], acc[r][3] + bv[3]);
    float4 o1 = make_float4(acc[r][4] + bv[4], acc[r][5] + bv[5],
                            acc[r][6] + bv[6], acc[r][7] + bv[7]);
    *(float4*)&dst[row * 128 + cc]     = o0;
    *(float4*)&dst[row * 128 + cc + 4] = o1;
  }
}

// ---------------------------------------------------------------------------
// Kernel 3: theta tail sums  TT[b][o] = sum_{j>=len} TH[b][j][o]
// ---------------------------------------------------------------------------
__global__ __launch_bounds__(128) void k_tail(
    const float* __restrict__ TH, const int* __restrict__ lens,
    float* __restrict__ TT) {
  int b = blockIdx.x, o = threadIdx.x;
  int len = lens[b];
  float s = 0.f;
  for (int j = len; j < L_; ++j) s += TH[((size_t)b * L_ + j) * EMB_ + o];
  TT[b * EMB_ + o] = s;
}

// ---------------------------------------------------------------------------
// Kernel 4: fused flash attention + tail correction + layernorm + row mask
// block = 16 query rows, 256 threads: thread (row = tid&15, g = tid>>4)
// owns output dims [g*8, g*8+8) of its row.
// ---------------------------------------------------------------------------
__global__ __launch_bounds__(256) void k_attn(
    const float* __restrict__ EA, const float* __restrict__ TH,
    const float* __restrict__ TT, const int* __restrict__ lens,
    const float* __restrict__ gamma, const float* __restrict__ beta,
    float* __restrict__ out) {
  const int b  = blockIdx.y;
  const int i0 = blockIdx.x * 16;
  const int len = lens[b];
  const int tid = threadIdx.x;
  const size_t obase = ((size_t)b * L_ + i0) * 128;

  if (i0 >= len) {  // whole tile masked -> zeros (output must be fully written)
    float4 z = make_float4(0.f, 0.f, 0.f, 0.f);
    for (int q = tid; q < 512; q += 256) *(float4*)&out[obase + (size_t)q * 4] = z;
    return;
  }

  __shared__ float EAi[16][132];
  __shared__ float EAj[16][132];
  __shared__ float THl[16][132];
  __shared__ float S[16][17];
  __shared__ float RED[2][16][17];

  const int row = tid & 15;
  const int g   = tid >> 4;

  // stage EA_i tile (EA is valid for all rows)
  for (int q = tid; q < 512; q += 256) {
    int r = q >> 5, k4 = (q & 31) * 4;
    *(float4*)&EAi[r][k4] = *(const float4*)&EA[((size_t)b * L_ + i0 + r) * 128 + k4];
  }

  float acc[8] = {0.f, 0.f, 0.f, 0.f, 0.f, 0.f, 0.f, 0.f};
  float m = 0.f;   // valid: masked columns contribute value 0, diag >= 0
  float l = 0.f;

  const int njt = (len + 15) >> 4;
  for (int jt = 0; jt < njt; ++jt) {
    const int j0 = jt * 16;
    __syncthreads();
    for (int q = tid; q < 512; q += 256) {
      int r = q >> 5, k4 = (q & 31) * 4;
      size_t src = ((size_t)b * L_ + j0 + r) * 128 + k4;
      *(float4*)&EAj[r][k4] = *(const float4*)&EA[src];
      *(float4*)&THl[r][k4] = *(const float4*)&TH[src];
    }
    __syncthreads();
    // scores: thread (row, g) computes s(row, j0+g)
    float s = 0.f;
#pragma unroll
    for (int k4 = 0; k4 < 128; k4 += 4) {
      float4 a  = *(const float4*)&EAi[row][k4];
      float4 bb = *(const float4*)&EAj[g][k4];
      s += a.x * bb.x + a.y * bb.y + a.z * bb.z + a.w * bb.w;
    }
    S[row][g] = fmaxf(s, 0.f);   // relu
    __syncthreads();

    const int jmax = min(16, len - j0);
    float mt = m;
    for (int jj = 0; jj < jmax; ++jj) mt = fmaxf(mt, S[row][jj]);
    float fac = __expf(m - mt);
    m = mt;
    l *= fac;
#pragma unroll
    for (int d = 0; d < 8; ++d) acc[d] *= fac;
    for (int jj = 0; jj < jmax; ++jj) {
      float w = __expf(S[row][jj] - m);
      l += w;
      float4 t0 = *(const float4*)&THl[jj][g * 8];
      float4 t1 = *(const float4*)&THl[jj][g * 8 + 4];
      acc[0] += w * t0.x; acc[1] += w * t0.y; acc[2] += w * t0.z; acc[3] += w * t0.w;
      acc[4] += w * t1.x; acc[5] += w * t1.y; acc[6] += w * t1.z; acc[7] += w * t1.w;
    }
  }

  // masked-column tail: L-len columns with score 0 -> weight e^{-m} each
  {
    float wt = __expf(-m);
    l += wt * (float)(L_ - len);
    const float* tt = &TT[b * EMB_ + g * 8];
    float4 t0 = *(const float4*)&tt[0];
    float4 t1 = *(const float4*)&tt[4];
    acc[0] += wt * t0.x; acc[1] += wt * t0.y; acc[2] += wt * t0.z; acc[3] += wt * t0.w;
    acc[4] += wt * t1.x; acc[5] += wt * t1.y; acc[6] += wt * t1.z; acc[7] += wt * t1.w;
  }
  const float inv = 1.f / l;
#pragma unroll
  for (int d = 0; d < 8; ++d) acc[d] *= inv;

  // layernorm over 128 dims (partials across the 16 g-threads of each row)
  float sm = 0.f, sq = 0.f;
#pragma unroll
  for (int d = 0; d < 8; ++d) { sm += acc[d]; sq += acc[d] * acc[d]; }
  __syncthreads();
  RED[0][row][g] = sm;
  RED[1][row][g] = sq;
  __syncthreads();
  float Sm = 0.f, Sq = 0.f;
  for (int q = 0; q < 16; ++q) { Sm += RED[0][row][q]; Sq += RED[1][row][q]; }
  const float mu   = Sm * (1.f / 128.f);
  const float var  = Sq * (1.f / 128.f) - mu * mu;
  const float rstd = rsqrtf(var + 1e-5f);

  const bool valid = (i0 + row) < len;
  const int dd = g * 8;
  float o[8];
#pragma unroll
  for (int d = 0; d < 8; ++d)
    o[d] = valid ? ((acc[d] - mu) * rstd * gamma[dd + d] + beta[dd + d]) : 0.f;
  *(float4*)&out[obase + (size_t)row * 128 + dd]     = make_float4(o[0], o[1], o[2], o[3]);
  *(float4*)&out[obase + (size_t)row * 128 + dd + 4] = make_float4(o[4], o[5], o[6], o[7]);
}

// ---------------------------------------------------------------------------
extern "C" void kernel_launch(void* const* d_in, const int* in_sizes, int n_in,
                              void* d_out, int out_size, void* d_ws, size_t ws_size,
                              hipStream_t stream) {
  const float* traj  = (const float*)d_in[0];
  const int*   lens  = (const int*)d_in[1];
  const float* W_ge  = (const float*)d_in[2];
  const float* b_ge  = (const float*)d_in[3];
  const float* W_eg  = (const float*)d_in[4];
  const float* b_eg  = (const float*)d_in[5];
  const float* Wg    = (const float*)d_in[6];
  const float* gamma = (const float*)d_in[7];
  const float* beta  = (const float*)d_in[8];
  float* out = (float*)d_out;

  // workspace layout (floats): Wc[256*128] bc[128] EA[B*L*128] TH[B*L*128] TT[B*128]
  float* ws = (float*)d_ws;
  float* Wc = ws;
  float* bc = Wc + DIN * EMB_;
  float* EA = bc + EMB_;
  float* TH = EA + (size_t)B_ * L_ * EMB_;
  float* TT = TH + (size_t)B_ * L_ * EMB_;

  k_fold<<<(DIN * EMB_ + EMB_ + 255) / 256, 256, 0, stream>>>(W_eg, b_eg, Wg, Wc, bc);
  k_embed<<<B_ * L_ / 32, 256, 0, stream>>>(traj, W_ge, b_ge, Wc, bc, EA, TH);
  k_tail<<<B_, 128, 0, stream>>>(TH, lens, TT);
  dim3 grid(L_ / 16, B_);
  k_attn<<<grid, 256, 0, stream>>>(EA, TH, TT, lens, gamma, beta, out);
}

// Round 2
// 237.554 us; speedup vs baseline: 2.9872x; 2.9872x over previous
//
#include <hip/hip_runtime.h>
#include <hip/hip_bf16.h>

#define B_   32
#define L_   1024
#define DIN  256
#define EMB_ 128

typedef __bf16 bf16x8 __attribute__((ext_vector_type(8)));
typedef float  f32x4  __attribute__((ext_vector_type(4)));
typedef unsigned short u16;

union U8 { u16 s[8]; bf16x8 v; };

__device__ __forceinline__ u16 f2b(float f) {
  union { float f; unsigned u; } v; v.f = f;
  unsigned r = (v.u + 0x7FFFu + ((v.u >> 16) & 1u)) >> 16;
  return (u16)r;
}
__device__ __forceinline__ float b2f(u16 h) {
  union { unsigned u; float f; } c; c.u = ((unsigned)h) << 16;
  return c.f;
}

// ---------------------------------------------------------------------------
// k_fold: Wc = W_eg@Wg folded+transposed into WbT rows 128..255 (bf16),
//         W_ge transposed into WbT rows 0..127, bc = b_eg@Wg (fp32), TT = 0.
// WbT[n][k] layout (row-major, 256 k per row) = MFMA A-operand friendly.
// ---------------------------------------------------------------------------
__global__ __launch_bounds__(256) void k_fold(
    const float* __restrict__ W_ge, const float* __restrict__ b_eg,
    const float* __restrict__ W_eg, const float* __restrict__ Wg,
    u16* __restrict__ WbT, float* __restrict__ bc, float* __restrict__ TT) {
  int idx = blockIdx.x * 256 + threadIdx.x;
  if (idx < 32768) {                       // Wc^T
    int d = idx >> 7, o = idx & 127;
    float s = 0.f;
    for (int k = 0; k < 128; ++k) s += W_eg[d * 128 + k] * Wg[k * 128 + o];
    WbT[(128 + o) * 256 + d] = f2b(s);
  } else if (idx < 65536) {                // W_ge^T
    int i = idx - 32768; int d = i >> 7, o = i & 127;
    WbT[o * 256 + d] = f2b(W_ge[d * 128 + o]);
  } else if (idx < 65664) {                // bc
    int o = idx - 65536;
    float s = 0.f;
    for (int k = 0; k < 128; ++k) s += b_eg[k] * Wg[k * 128 + o];
    bc[o] = s;
  } else if (idx < 65664 + 4096) {         // zero TT (ws is poisoned)
    TT[idx - 65664] = 0.f;
  }
}

// ---------------------------------------------------------------------------
// k_embed: [EA|TH](bf16) = traj @ [W_ge|Wc] + bias via MFMA.
// D[n][m]: A = WbT rows (n,k) staged in LDS, B = traj (k,m) bf16-converted.
// Block = 4 waves x 16 traj rows. Lane: m = l&15, n = ntile*16 + 4g + r.
// ---------------------------------------------------------------------------
__global__ __launch_bounds__(256) void k_embed(
    const float* __restrict__ traj, const u16* __restrict__ WbT,
    const float* __restrict__ b_ge, const float* __restrict__ bc,
    u16* __restrict__ EA, u16* __restrict__ TH) {
  __shared__ u16 Ws[256][40];              // padded stride 40 bf16 = 80B
  const int tid = threadIdx.x;
  const int wv = tid >> 6, ln = tid & 63;
  const int li = ln & 15, g = ln >> 4;
  const int row = blockIdx.x * 64 + wv * 16 + li;

  f32x4 acc[16] = {};

  for (int kc = 0; kc < 8; ++kc) {
    __syncthreads();
    {  // stage 32-k weight slab for all 256 n
      const u16* src = &WbT[tid * 256 + kc * 32];
      *(bf16x8*)&Ws[tid][0]  = *(const bf16x8*)&src[0];
      *(bf16x8*)&Ws[tid][8]  = *(const bf16x8*)&src[8];
      *(bf16x8*)&Ws[tid][16] = *(const bf16x8*)&src[16];
      *(bf16x8*)&Ws[tid][24] = *(const bf16x8*)&src[24];
    }
    __syncthreads();
    U8 bu;
    {  // B-frag: traj[row][kc*32 + g*8 ..+8] fp32 -> bf16
      const float* p = &traj[(size_t)row * DIN + kc * 32 + g * 8];
      float4 v0 = *(const float4*)p;
      float4 v1 = *(const float4*)(p + 4);
      bu.s[0]=f2b(v0.x); bu.s[1]=f2b(v0.y); bu.s[2]=f2b(v0.z); bu.s[3]=f2b(v0.w);
      bu.s[4]=f2b(v1.x); bu.s[5]=f2b(v1.y); bu.s[6]=f2b(v1.z); bu.s[7]=f2b(v1.w);
    }
#pragma unroll
    for (int nd = 0; nd < 16; ++nd) {
      bf16x8 afrag = *(const bf16x8*)&Ws[nd * 16 + li][g * 8];
      acc[nd] = __builtin_amdgcn_mfma_f32_16x16x32_bf16(afrag, bu.v, acc[nd], 0, 0, 0);
    }
  }
#pragma unroll
  for (int nd = 0; nd < 16; ++nd) {
    int ncol = nd * 16 + 4 * g;
    u16 pk[4];
#pragma unroll
    for (int r = 0; r < 4; ++r) {
      int n = ncol + r;
      float bias = (n < 128) ? b_ge[n] : bc[n - 128];
      pk[r] = f2b(acc[nd][r] + bias);
    }
    u16* dst = (ncol < 128) ? &EA[(size_t)row * 128 + ncol]
                            : &TH[(size_t)row * 128 + (ncol - 128)];
    *(uint2*)dst = *(uint2*)pk;
  }
}

// ---------------------------------------------------------------------------
// k_tail: TT[b][o] += sum_{j>=len} TH[b][j][o]   (4-way split over j, atomics)
// ---------------------------------------------------------------------------
__global__ __launch_bounds__(128) void k_tail(
    const u16* __restrict__ TH, const int* __restrict__ lens,
    float* __restrict__ TT) {
  int b = blockIdx.x, c = blockIdx.y, o = threadIdx.x;
  int len = lens[b];
  float s = 0.f;
  for (int j = len + c; j < L_; j += 4)
    s += b2f(TH[((size_t)b * L_ + j) * 128 + o]);
  atomicAdd(&TT[b * 128 + o], s);
}

// ---------------------------------------------------------------------------
// k_attn: flash attention + masked-column tail + layernorm + row mask.
// Block = 64 q rows (4 waves x 16), j-tile = 32.
// Lane owns rows i = wv*16 + 4g + r (r=0..3), cols d/j = li (per 16-subtile).
// ---------------------------------------------------------------------------
#define VSTR 40
#define PSTR 40

__global__ __launch_bounds__(256) void k_attn(
    const u16* __restrict__ EA, const u16* __restrict__ TH,
    const float* __restrict__ TT, const int* __restrict__ lens,
    const float* __restrict__ gamma, const float* __restrict__ beta,
    float* __restrict__ out) {
  const int b  = blockIdx.y;
  const int i0 = blockIdx.x * 64;
  const int len = lens[b];
  const int tid = threadIdx.x;
  const size_t obase = ((size_t)b * L_ + i0) * 128;

  if (i0 >= len) {
    float4 z = {0.f, 0.f, 0.f, 0.f};
    for (int q = tid; q < 2048; q += 256) *(float4*)&out[obase + (size_t)q * 4] = z;
    return;
  }

  __shared__ u16 Klds[32 * 128];       // XOR-swizzled rows (256B each)
  __shared__ u16 Vlds[128 * VSTR];     // VT[d][j], padded
  __shared__ u16 Plds[4][16 * PSTR];   // per-wave P tile [i][j]

  const int wv = tid >> 6, ln = tid & 63;
  const int li = ln & 15, g = ln >> 4;
  const size_t ebase = (size_t)b * L_ * 128;

  // Q fragments (rows i0 + wv*16 + li), hoisted
  bf16x8 qf[4];
  {
    const u16* qp = &EA[ebase + (size_t)(i0 + wv * 16 + li) * 128 + g * 8];
#pragma unroll
    for (int kc = 0; kc < 4; ++kc) qf[kc] = *(const bf16x8*)&qp[kc * 32];
  }

  f32x4 Oa[8] = {};
  float m[4] = {0.f, 0.f, 0.f, 0.f};      // valid: all scores >= 0 (relu)
  float lsum[4] = {0.f, 0.f, 0.f, 0.f};

  const int njt = (len + 31) >> 5;
  for (int jt = 0; jt < njt; ++jt) {
    const int j0 = jt * 32;
    __syncthreads();
    {  // stage K (swizzled) and V^T
      int jr = tid >> 3, ch = tid & 7;
      const char* ksrc = (const char*)&EA[ebase + (size_t)(j0 + jr) * 128];
      const char* vsrc = (const char*)&TH[ebase + (size_t)(j0 + jr) * 128];
#pragma unroll
      for (int it = 0; it < 2; ++it) {
        int cb = (ch + it * 8) * 16;     // byte offset within row
        *(bf16x8*)((char*)&Klds[jr * 128] + (cb ^ ((jr & 7) << 4))) =
            *(const bf16x8*)(ksrc + cb);
        U8 tv; tv.v = *(const bf16x8*)(vsrc + cb);
        int d0 = cb / 2;                 // first d of this chunk
#pragma unroll
        for (int e = 0; e < 8; ++e) Vlds[(d0 + e) * VSTR + jr] = tv.s[e];
      }
    }
    __syncthreads();

    // QK^T: S[n] = Q(16x128) . K^T, n-subtile = j local 16
    f32x4 S[2] = {};
#pragma unroll
    for (int n = 0; n < 2; ++n) {
      int krow = n * 16 + li;
      const char* kb = (const char*)&Klds[krow * 128];
#pragma unroll
      for (int kc = 0; kc < 4; ++kc) {
        bf16x8 kf = *(const bf16x8*)(kb + ((kc * 64 + g * 16) ^ ((krow & 7) << 4)));
        S[n] = __builtin_amdgcn_mfma_f32_16x16x32_bf16(qf[kc], kf, S[n], 0, 0, 0);
      }
    }

    // relu + in-tile mask + online softmax (rows 4g+r, reduce over 16 lanes)
    const bool v0 = (j0 + li) < len;
    const bool v1 = (j0 + 16 + li) < len;
    float x[4];
#pragma unroll
    for (int r = 0; r < 4; ++r) {
      float s0 = v0 ? fmaxf(S[0][r], 0.f) : 0.f;
      float s1 = v1 ? fmaxf(S[1][r], 0.f) : 0.f;
      S[0][r] = s0; S[1][r] = s1;
      x[r] = fmaxf(s0, s1);
    }
#pragma unroll
    for (int d = 1; d < 16; d <<= 1)
#pragma unroll
      for (int r = 0; r < 4; ++r) x[r] = fmaxf(x[r], __shfl_xor(x[r], d, 16));

    float p0[4], p1[4], fac[4], y[4];
#pragma unroll
    for (int r = 0; r < 4; ++r) {
      float mt = fmaxf(m[r], x[r]);
      fac[r] = __expf(m[r] - mt);
      m[r] = mt;
      p0[r] = v0 ? __expf(S[0][r] - mt) : 0.f;
      p1[r] = v1 ? __expf(S[1][r] - mt) : 0.f;
      y[r] = p0[r] + p1[r];
    }
#pragma unroll
    for (int d = 1; d < 16; d <<= 1)
#pragma unroll
      for (int r = 0; r < 4; ++r) y[r] += __shfl_xor(y[r], d, 16);
#pragma unroll
    for (int r = 0; r < 4; ++r) lsum[r] = lsum[r] * fac[r] + y[r];
#pragma unroll
    for (int t = 0; t < 8; ++t)
#pragma unroll
      for (int r = 0; r < 4; ++r) Oa[t][r] *= fac[r];

    // P -> per-wave LDS (bf16), then PV via MFMA
    u16* pl = Plds[wv];
#pragma unroll
    for (int r = 0; r < 4; ++r) {
      pl[(4 * g + r) * PSTR + li]      = f2b(p0[r]);
      pl[(4 * g + r) * PSTR + 16 + li] = f2b(p1[r]);
    }
    bf16x8 pf = *(const bf16x8*)&pl[li * PSTR + g * 8];
#pragma unroll
    for (int t = 0; t < 8; ++t) {
      bf16x8 vf = *(const bf16x8*)&Vlds[(t * 16 + li) * VSTR + g * 8];
      Oa[t] = __builtin_amdgcn_mfma_f32_16x16x32_bf16(pf, vf, Oa[t], 0, 0, 0);
    }
  }

  // masked-column tail: (L-len) cols, score 0 -> weight e^{-m}
  {
    const float* tt = &TT[b * 128];
#pragma unroll
    for (int r = 0; r < 4; ++r) {
      float wt = __expf(-m[r]);
      lsum[r] += wt * (float)(L_ - len);
#pragma unroll
      for (int t = 0; t < 8; ++t) Oa[t][r] += wt * tt[t * 16 + li];
    }
  }

  // normalize + layernorm stats
  float sm[4] = {0.f, 0.f, 0.f, 0.f}, sq[4] = {0.f, 0.f, 0.f, 0.f};
#pragma unroll
  for (int r = 0; r < 4; ++r) {
    float inv = 1.f / lsum[r];
#pragma unroll
    for (int t = 0; t < 8; ++t) {
      float val = Oa[t][r] * inv;
      Oa[t][r] = val;
      sm[r] += val; sq[r] += val * val;
    }
  }
#pragma unroll
  for (int d = 1; d < 16; d <<= 1)
#pragma unroll
    for (int r = 0; r < 4; ++r) {
      sm[r] += __shfl_xor(sm[r], d, 16);
      sq[r] += __shfl_xor(sq[r], d, 16);
    }

  const int irow = i0 + wv * 16;
#pragma unroll
  for (int r = 0; r < 4; ++r) {
    float mu  = sm[r] * (1.f / 128.f);
    float var = sq[r] * (1.f / 128.f) - mu * mu;
    float rstd = rsqrtf(var + 1e-5f);
    int i = irow + 4 * g + r;
    bool valid = i < len;
#pragma unroll
    for (int t = 0; t < 8; ++t) {
      int dcol = t * 16 + li;
      float o = valid ? ((Oa[t][r] - mu) * rstd * gamma[dcol] + beta[dcol]) : 0.f;
      out[((size_t)b * L_ + i) * 128 + dcol] = o;
    }
  }
}

// ---------------------------------------------------------------------------
extern "C" void kernel_launch(void* const* d_in, const int* in_sizes, int n_in,
                              void* d_out, int out_size, void* d_ws, size_t ws_size,
                              hipStream_t stream) {
  const float* traj  = (const float*)d_in[0];
  const int*   lens  = (const int*)d_in[1];
  const float* W_ge  = (const float*)d_in[2];
  const float* b_ge  = (const float*)d_in[3];
  const float* W_eg  = (const float*)d_in[4];
  const float* b_eg  = (const float*)d_in[5];
  const float* Wg    = (const float*)d_in[6];
  const float* gamma = (const float*)d_in[7];
  const float* beta  = (const float*)d_in[8];
  float* out = (float*)d_out;

  // workspace: WbT bf16[256*256] | bc f32[128] | TT f32[32*128] | EA bf16 | TH bf16
  char* ws = (char*)d_ws;
  u16*   WbT = (u16*)ws;
  float* bc  = (float*)(ws + 131072);
  float* TT  = (float*)(ws + 131072 + 512);
  u16*   EA  = (u16*)(ws + 131072 + 512 + 16384);
  u16*   TH  = EA + (size_t)B_ * L_ * 128;

  k_fold<<<273, 256, 0, stream>>>(W_ge, b_eg, W_eg, Wg, WbT, bc, TT);
  k_embed<<<512, 256, 0, stream>>>(traj, WbT, b_ge, bc, EA, TH);
  k_tail<<<dim3(32, 4), 128, 0, stream>>>(TH, lens, TT);
  k_attn<<<dim3(16, 32), 256, 0, stream>>>(EA, TH, TT, lens, gamma, beta, out);
}

// Round 4
// 218.453 us; speedup vs baseline: 3.2484x; 1.0874x over previous
//
#include <hip/hip_runtime.h>
#include <hip/hip_bf16.h>

#define B_   32
#define L_   1024
#define DIN  256
#define EMB_ 128

typedef __bf16 bf16x8 __attribute__((ext_vector_type(8)));
typedef float  f32x4  __attribute__((ext_vector_type(4)));
typedef unsigned short u16;

union U8 { u16 s[8]; bf16x8 v; };
union VU { uint2 p[2]; bf16x8 v; };

__device__ __forceinline__ u16 f2b(float f) {
  union { float f; unsigned u; } v; v.f = f;
  unsigned r = (v.u + 0x7FFFu + ((v.u >> 16) & 1u)) >> 16;
  return (u16)r;
}
__device__ __forceinline__ float b2f(u16 h) {
  union { unsigned u; float f; } c; c.u = ((unsigned)h) << 16;
  return c.f;
}

// HW transpose-read (crossbar semantics, m156/m162):
// each lane fetches 8B at its own addr; 16-lane group spans 128B = 4 rows x
// 16 bf16; lane l receives column (l&15) of those 4 rows.
#define TR16_0(dst, addr) \
  asm volatile("ds_read_b64_tr_b16 %0, %1 offset:0" : "=v"(dst) : "v"(addr))
#define TR16_128(dst, addr) \
  asm volatile("ds_read_b64_tr_b16 %0, %1 offset:128" : "=v"(dst) : "v"(addr))

// ---------------------------------------------------------------------------
// k_fold: WbT rows 0..127 = W_ge^T, rows 128..255 = (W_eg@Wg)^T (bf16);
//         bc = b_eg@Wg (f32); TT zeroed.
// ---------------------------------------------------------------------------
__global__ __launch_bounds__(256) void k_fold(
    const float* __restrict__ W_ge, const float* __restrict__ b_eg,
    const float* __restrict__ W_eg, const float* __restrict__ Wg,
    u16* __restrict__ WbT, float* __restrict__ bc, float* __restrict__ TT) {
  int idx = blockIdx.x * 256 + threadIdx.x;
  if (idx < 32768) {                       // Wc^T
    int d = idx >> 7, o = idx & 127;
    float s = 0.f;
    for (int k = 0; k < 128; ++k) s += W_eg[d * 128 + k] * Wg[k * 128 + o];
    WbT[(128 + o) * 256 + d] = f2b(s);
  } else if (idx < 65536) {                // W_ge^T
    int i = idx - 32768; int d = i >> 7, o = i & 127;
    WbT[o * 256 + d] = f2b(W_ge[d * 128 + o]);
  } else if (idx < 65664) {                // bc
    int o = idx - 65536;
    float s = 0.f;
    for (int k = 0; k < 128; ++k) s += b_eg[k] * Wg[k * 128 + o];
    bc[o] = s;
  } else if (idx < 65664 + 4096) {         // zero TT (ws is poisoned)
    TT[idx - 65664] = 0.f;
  }
}

// ---------------------------------------------------------------------------
// k_embed: [EA|TH](bf16) = traj @ [W_ge|Wc] + bias via MFMA.
// EA half skipped for 64-row blocks fully beyond len (EA_j unused there;
// TH needed everywhere for the tail correction).
// ---------------------------------------------------------------------------
__global__ __launch_bounds__(256) void k_embed(
    const float* __restrict__ traj, const u16* __restrict__ WbT,
    const float* __restrict__ b_ge, const float* __restrict__ bc,
    const int* __restrict__ lens,
    u16* __restrict__ EA, u16* __restrict__ TH) {
  __shared__ u16 Ws[256][40];              // stride 40 u16 = 80B (aligned b128)
  const int tid = threadIdx.x;
  const int wv = tid >> 6, ln = tid & 63;
  const int li = ln & 15, g = ln >> 4;
  const int row = blockIdx.x * 64 + wv * 16 + li;
  const int b = blockIdx.x >> 4;           // 16 blocks per batch
  const int len = lens[b];
  const int nd0 = (((blockIdx.x & 15) * 64) < len) ? 0 : 8;

  // hoist traj row -> 8 bf16 B-fragments
  bf16x8 tf[8];
  {
    const float* tp = &traj[(size_t)row * DIN];
#pragma unroll
    for (int t = 0; t < 8; ++t) {
      float4 v0 = *(const float4*)(tp + t * 32 + g * 8);
      float4 v1 = *(const float4*)(tp + t * 32 + g * 8 + 4);
      U8 bu;
      bu.s[0]=f2b(v0.x); bu.s[1]=f2b(v0.y); bu.s[2]=f2b(v0.z); bu.s[3]=f2b(v0.w);
      bu.s[4]=f2b(v1.x); bu.s[5]=f2b(v1.y); bu.s[6]=f2b(v1.z); bu.s[7]=f2b(v1.w);
      tf[t] = bu.v;
    }
  }

  f32x4 acc[16] = {};

  for (int kc = 0; kc < 8; ++kc) {
    __syncthreads();
    if (nd0 == 0 || tid >= 128) {          // stage only needed n-rows
      const u16* src = &WbT[tid * 256 + kc * 32];
      *(bf16x8*)&Ws[tid][0]  = *(const bf16x8*)&src[0];
      *(bf16x8*)&Ws[tid][8]  = *(const bf16x8*)&src[8];
      *(bf16x8*)&Ws[tid][16] = *(const bf16x8*)&src[16];
      *(bf16x8*)&Ws[tid][24] = *(const bf16x8*)&src[24];
    }
    __syncthreads();
#pragma unroll
    for (int nd = 0; nd < 16; ++nd) {
      if (nd < nd0) continue;
      bf16x8 afrag = *(const bf16x8*)&Ws[nd * 16 + li][g * 8];
      acc[nd] = __builtin_amdgcn_mfma_f32_16x16x32_bf16(afrag, tf[kc], acc[nd], 0, 0, 0);
    }
  }
#pragma unroll
  for (int nd = 0; nd < 16; ++nd) {
    if (nd < nd0) continue;
    int ncol = nd * 16 + 4 * g;
    u16 pk[4];
#pragma unroll
    for (int r = 0; r < 4; ++r) {
      int n = ncol + r;
      float bias = (n < 128) ? b_ge[n] : bc[n - 128];
      pk[r] = f2b(acc[nd][r] + bias);
    }
    u16* dst = (ncol < 128) ? &EA[(size_t)row * 128 + ncol]
                            : &TH[(size_t)row * 128 + (ncol - 128)];
    *(uint2*)dst = *(uint2*)pk;
  }
}

// ---------------------------------------------------------------------------
// k_tail: TT[b][o] += sum_{j in [max(len,c*64),(c+1)*64)} TH[b][j][o]
// ---------------------------------------------------------------------------
__global__ __launch_bounds__(128) void k_tail(
    const u16* __restrict__ TH, const int* __restrict__ lens,
    float* __restrict__ TT) {
  int b = blockIdx.x, c = blockIdx.y, o = threadIdx.x;
  int len = lens[b];
  int jlo = max(len, c * 64), jhi = (c + 1) * 64;
  if (jlo >= jhi) return;
  float s = 0.f;
  for (int j = jlo; j < jhi; ++j)
    s += b2f(TH[((size_t)b * L_ + j) * 128 + o]);
  atomicAdd(&TT[b * 128 + o], s);
}

// ---------------------------------------------------------------------------
// k_attn: flash attention + masked-column tail + layernorm + row mask.
// Block = 32 q rows (2 waves x 16), j-tile = 32, grid 32x32.
// K: XOR-swizzled rows. V: subtiled [8 t][32 j][16 d] for ds_read_b64_tr_b16.
// ---------------------------------------------------------------------------
#define VSTEP 512   // u16 per t-region
#define PSTR  40

__global__ __launch_bounds__(128) void k_attn(
    const u16* __restrict__ EA, const u16* __restrict__ TH,
    const float* __restrict__ TT, const int* __restrict__ lens,
    const float* __restrict__ gamma, const float* __restrict__ beta,
    float* __restrict__ out) {
  const int b  = blockIdx.y;
  const int i0 = blockIdx.x * 32;
  const int len = lens[b];
  const int tid = threadIdx.x;
  const size_t obase = ((size_t)b * L_ + i0) * 128;

  if (i0 >= len) {                         // fully masked tile -> zeros
    float4 z = {0.f, 0.f, 0.f, 0.f};
    for (int q = tid; q < 1024; q += 128) *(float4*)&out[obase + (size_t)q * 4] = z;
    return;
  }

  __shared__ u16 Klds[32 * 128];           // swizzled rows, 8KB
  __shared__ u16 Vlds[8 * VSTEP];          // [t][j][16], 8KB
  __shared__ u16 Plds[2][16 * PSTR];       // per-wave P tile

  const int wv = tid >> 6, ln = tid & 63;
  const int li = ln & 15, g = ln >> 4;
  const size_t ebase = (size_t)b * L_ * 128;

  // Q fragments, hoisted
  bf16x8 qf[4];
  {
    const u16* qp = &EA[ebase + (size_t)(i0 + wv * 16 + li) * 128 + g * 8];
#pragma unroll
    for (int kc = 0; kc < 4; ++kc) qf[kc] = *(const bf16x8*)&qp[kc * 32];
  }

  // tr-read base: lane fetches its own 8B within the 4-row (128B) group span
  const unsigned vtr_base = (unsigned)(size_t)&Vlds[0] + g * 256 + li * 8;

  f32x4 Oa[8] = {};
  float m[4] = {0.f, 0.f, 0.f, 0.f};
  float lsum[4] = {0.f, 0.f, 0.f, 0.f};

  const int jr = tid >> 2;                 // staging: row 0..31
  const int ch = tid & 3;                  // chunk group

  const int njt = (len + 31) >> 5;
  for (int jt = 0; jt < njt; ++jt) {
    const int j0 = jt * 32;
    __syncthreads();
    {  // stage K (swizzled) and V (subtiled), b128 writes only
      const char* ksrc = (const char*)&EA[ebase + (size_t)(j0 + jr) * 128];
      const char* vsrc = (const char*)&TH[ebase + (size_t)(j0 + jr) * 128];
#pragma unroll
      for (int k = 0; k < 4; ++k) {
        int cb = (ch + 4 * k) * 16;        // byte offset in row, 0..240
        *(bf16x8*)((char*)Klds + jr * 256 + (cb ^ ((jr & 7) << 4))) =
            *(const bf16x8*)(ksrc + cb);
        bf16x8 vv = *(const bf16x8*)(vsrc + cb);
        int d0 = cb >> 1;                  // first d (multiple of 8)
        *(bf16x8*)&Vlds[(d0 >> 4) * VSTEP + jr * 16 + (d0 & 15)] = vv;
      }
    }
    __syncthreads();

    // QK^T: S = Q(16x128) . K^T
    f32x4 S[2] = {};
#pragma unroll
    for (int n = 0; n < 2; ++n) {
      int krow = n * 16 + li;
      const char* kb = (const char*)&Klds[krow * 128];
#pragma unroll
      for (int kc = 0; kc < 4; ++kc) {
        bf16x8 kf = *(const bf16x8*)(kb + ((kc * 64 + g * 16) ^ ((krow & 7) << 4)));
        S[n] = __builtin_amdgcn_mfma_f32_16x16x32_bf16(qf[kc], kf, S[n], 0, 0, 0);
      }
    }

    // issue V transpose-reads early (overlap with softmax VALU)
    uint2 vr[16];
#pragma unroll
    for (int t = 0; t < 8; ++t) {
      unsigned a = vtr_base + t * 1024;
      TR16_0(vr[2 * t], a);
      TR16_128(vr[2 * t + 1], a);
    }

    // relu + in-tile mask + online softmax
    const bool v0 = (j0 + li) < len;
    const bool v1 = (j0 + 16 + li) < len;
    float x[4];
#pragma unroll
    for (int r = 0; r < 4; ++r) {
      float s0 = v0 ? fmaxf(S[0][r], 0.f) : 0.f;
      float s1 = v1 ? fmaxf(S[1][r], 0.f) : 0.f;
      S[0][r] = s0; S[1][r] = s1;
      x[r] = fmaxf(s0, s1);
    }
#pragma unroll
    for (int d = 1; d < 16; d <<= 1)
#pragma unroll
      for (int r = 0; r < 4; ++r) x[r] = fmaxf(x[r], __shfl_xor(x[r], d, 16));

    float p0[4], p1[4], fac[4], y[4];
#pragma unroll
    for (int r = 0; r < 4; ++r) {
      float mt = fmaxf(m[r], x[r]);
      fac[r] = __expf(m[r] - mt);
      m[r] = mt;
      p0[r] = v0 ? __expf(S[0][r] - mt) : 0.f;
      p1[r] = v1 ? __expf(S[1][r] - mt) : 0.f;
      y[r] = p0[r] + p1[r];
    }
#pragma unroll
    for (int d = 1; d < 16; d <<= 1)
#pragma unroll
      for (int r = 0; r < 4; ++r) y[r] += __shfl_xor(y[r], d, 16);
#pragma unroll
    for (int r = 0; r < 4; ++r) lsum[r] = lsum[r] * fac[r] + y[r];
#pragma unroll
    for (int t = 0; t < 8; ++t)
#pragma unroll
      for (int r = 0; r < 4; ++r) Oa[t][r] *= fac[r];

    // P -> per-wave LDS, read back as A-fragment
    u16* pl = Plds[wv];
#pragma unroll
    for (int r = 0; r < 4; ++r) {
      pl[(4 * g + r) * PSTR + li]      = f2b(p0[r]);
      pl[(4 * g + r) * PSTR + 16 + li] = f2b(p1[r]);
    }
    bf16x8 pf = *(const bf16x8*)&pl[li * PSTR + g * 8];

    // drain all LDS (tr-reads + pf) before consuming; fence rule #18
    asm volatile("s_waitcnt lgkmcnt(0)" ::: "memory");
    __builtin_amdgcn_sched_barrier(0);

#pragma unroll
    for (int t = 0; t < 8; ++t) {
      VU vu; vu.p[0] = vr[2 * t]; vu.p[1] = vr[2 * t + 1];
      Oa[t] = __builtin_amdgcn_mfma_f32_16x16x32_bf16(pf, vu.v, Oa[t], 0, 0, 0);
    }
  }

  // masked-column tail: (L-len) cols with score 0 -> weight e^{-m}
  {
    float tt8[8];
#pragma unroll
    for (int t = 0; t < 8; ++t) tt8[t] = TT[b * 128 + t * 16 + li];
#pragma unroll
    for (int r = 0; r < 4; ++r) {
      float wt = __expf(-m[r]);
      lsum[r] += wt * (float)(L_ - len);
#pragma unroll
      for (int t = 0; t < 8; ++t) Oa[t][r] += wt * tt8[t];
    }
  }

  // normalize + layernorm
  float sm[4] = {0.f, 0.f, 0.f, 0.f}, sq[4] = {0.f, 0.f, 0.f, 0.f};
#pragma unroll
  for (int r = 0; r < 4; ++r) {
    float inv = 1.f / lsum[r];
#pragma unroll
    for (int t = 0; t < 8; ++t) {
      float val = Oa[t][r] * inv;
      Oa[t][r] = val;
      sm[r] += val; sq[r] += val * val;
    }
  }
#pragma unroll
  for (int d = 1; d < 16; d <<= 1)
#pragma unroll
    for (int r = 0; r < 4; ++r) {
      sm[r] += __shfl_xor(sm[r], d, 16);
      sq[r] += __shfl_xor(sq[r], d, 16);
    }

  const int irow = i0 + wv * 16;
#pragma unroll
  for (int r = 0; r < 4; ++r) {
    float mu  = sm[r] * (1.f / 128.f);
    float var = sq[r] * (1.f / 128.f) - mu * mu;
    float rstd = rsqrtf(var + 1e-5f);
    int i = irow + 4 * g + r;
    bool valid = i < len;
#pragma unroll
    for (int t = 0; t < 8; ++t) {
      int dcol = t * 16 + li;
      float o = valid ? ((Oa[t][r] - mu) * rstd * gamma[dcol] + beta[dcol]) : 0.f;
      out[((size_t)b * L_ + i) * 128 + dcol] = o;
    }
  }
}

// ---------------------------------------------------------------------------
extern "C" void kernel_launch(void* const* d_in, const int* in_sizes, int n_in,
                              void* d_out, int out_size, void* d_ws, size_t ws_size,
                              hipStream_t stream) {
  const float* traj  = (const float*)d_in[0];
  const int*   lens  = (const int*)d_in[1];
  const float* W_ge  = (const float*)d_in[2];
  const float* b_ge  = (const float*)d_in[3];
  const float* W_eg  = (const float*)d_in[4];
  const float* b_eg  = (const float*)d_in[5];
  const float* Wg    = (const float*)d_in[6];
  const float* gamma = (const float*)d_in[7];
  const float* beta  = (const float*)d_in[8];
  float* out = (float*)d_out;

  // workspace: WbT bf16[256*256] | bc f32[128] | TT f32[32*128] | EA bf16 | TH bf16
  char* ws = (char*)d_ws;
  u16*   WbT = (u16*)ws;
  float* bc  = (float*)(ws + 131072);
  float* TT  = (float*)(ws + 131072 + 512);
  u16*   EA  = (u16*)(ws + 131072 + 512 + 16384);
  u16*   TH  = EA + (size_t)B_ * L_ * 128;

  k_fold<<<273, 256, 0, stream>>>(W_ge, b_eg, W_eg, Wg, WbT, bc, TT);
  k_embed<<<512, 256, 0, stream>>>(traj, WbT, b_ge, bc, lens, EA, TH);
  k_tail<<<dim3(32, 16), 128, 0, stream>>>(TH, lens, TT);
  k_attn<<<dim3(32, 32), 128, 0, stream>>>(EA, TH, TT, lens, gamma, beta, out);
}

// Round 8
// 173.681 us; speedup vs baseline: 4.0857x; 1.2578x over previous
//
#include <hip/hip_runtime.h>
#include <hip/hip_bf16.h>

#define B_   32
#define L_   1024
#define DIN  256

typedef __bf16 bf16x8 __attribute__((ext_vector_type(8)));
typedef float  f32x4  __attribute__((ext_vector_type(4)));
typedef unsigned short u16;

union U8 { u16 s[8]; bf16x8 v; };
union VU { uint2 p[2]; bf16x8 v; };

__device__ __forceinline__ u16 f2b(float f) {
  union { float f; unsigned u; } v; v.f = f;
  unsigned r = (v.u + 0x7FFFu + ((v.u >> 16) & 1u)) >> 16;
  return (u16)r;
}
__device__ __forceinline__ float b2f(u16 h) {
  union { unsigned u; float f; } c; c.u = ((unsigned)h) << 16;
  return c.f;
}

// HW transpose-read: lane fetches 8B at its addr; 16-lane group spans 128B =
// 4 rows x 16 bf16; lane l receives column (l&15) of those 4 rows.
// Early-clobber: dst must NOT alias the addr register (async completion).
#define TR16_0(dst, addr) \
  asm volatile("ds_read_b64_tr_b16 %0, %1 offset:0" : "=&v"(dst) : "v"(addr))
#define TR16_128(dst, addr) \
  asm volatile("ds_read_b64_tr_b16 %0, %1 offset:128" : "=&v"(dst) : "v"(addr))

// ---------------------------------------------------------------------------
// k_fold: WbT rows 0..127 = W_ge^T, rows 128..255 = (W_eg@Wg)^T (bf16);
//         bc = b_eg@Wg (f32); TT zeroed.
// ---------------------------------------------------------------------------
__global__ __launch_bounds__(256) void k_fold(
    const float* __restrict__ W_ge, const float* __restrict__ b_eg,
    const float* __restrict__ W_eg, const float* __restrict__ Wg,
    u16* __restrict__ WbT, float* __restrict__ bc, float* __restrict__ TT) {
  int idx = blockIdx.x * 256 + threadIdx.x;
  if (idx < 32768) {                       // Wc^T
    int d = idx >> 7, o = idx & 127;
    float s = 0.f;
    for (int k = 0; k < 128; ++k) s += W_eg[d * 128 + k] * Wg[k * 128 + o];
    WbT[(128 + o) * 256 + d] = f2b(s);
  } else if (idx < 65536) {                // W_ge^T
    int i = idx - 32768; int d = i >> 7, o = i & 127;
    WbT[o * 256 + d] = f2b(W_ge[d * 128 + o]);
  } else if (idx < 65664) {                // bc
    int o = idx - 65536;
    float s = 0.f;
    for (int k = 0; k < 128; ++k) s += b_eg[k] * Wg[k * 128 + o];
    bc[o] = s;
  } else if (idx < 65664 + 4096) {         // zero TT (ws is poisoned)
    TT[idx - 65664] = 0.f;
  }
}

// ---------------------------------------------------------------------------
// k_embed: [EA|TH](bf16) = traj @ [W_ge|Wc] + bias via MFMA, tail sums fused.
// 256 blocks x 512 threads (8 waves), 128 traj rows per block.
// Full weight matrix staged once in LDS; zero in-loop barriers. EA half
// skipped for blocks fully beyond len. Tail: Sum_{row>=len} TH -> TT.
// ---------------------------------------------------------------------------
__global__ __launch_bounds__(512) void k_embed(
    const float* __restrict__ traj, const u16* __restrict__ WbT,
    const float* __restrict__ b_ge, const float* __restrict__ bc,
    const int* __restrict__ lens,
    u16* __restrict__ EA, u16* __restrict__ TH, float* __restrict__ TT) {
  __shared__ u16 Ws[256][264];
  __shared__ float tailLds[128];
  const int tid = threadIdx.x;
  const int wv = tid >> 6, ln = tid & 63;
  const int li = ln & 15, g = ln >> 4;
  const int b   = blockIdx.x >> 3;
  const int rl0 = (blockIdx.x & 7) * 128;
  const int len = lens[b];
  const int rw  = rl0 + wv * 16 + li;          // row within batch
  const size_t row = (size_t)b * L_ + rw;
  const int nd0 = (rl0 >= len) ? 8 : 0;        // skip EA for fully-masked blk
  const bool doTail = (rl0 + 128 > len);

  if (tid < 128) tailLds[tid] = 0.f;

  {  // stage full weights: thread stages 128 u16 = half of row tid>>1.
     // (round-5/6 BUG was here: stride 16 with 8 iters staged only half ->
     //  uninitialized LDS (NaN patterns) fed the MFMA. Now 16 iters x 8 u16.)
    const u16* src = &WbT[(tid >> 1) * 256 + (tid & 1) * 128];
    u16* dst = &Ws[tid >> 1][(tid & 1) * 128];
#pragma unroll
    for (int i = 0; i < 16; ++i)
      *(bf16x8*)&dst[i * 8] = *(const bf16x8*)&src[i * 8];
  }

  // traj row -> 8 bf16 B-fragments
  bf16x8 tf[8];
  {
    const float* tp = &traj[row * DIN];
#pragma unroll
    for (int t = 0; t < 8; ++t) {
      float4 v0 = *(const float4*)(tp + t * 32 + g * 8);
      float4 v1 = *(const float4*)(tp + t * 32 + g * 8 + 4);
      U8 bu;
      bu.s[0]=f2b(v0.x); bu.s[1]=f2b(v0.y); bu.s[2]=f2b(v0.z); bu.s[3]=f2b(v0.w);
      bu.s[4]=f2b(v1.x); bu.s[5]=f2b(v1.y); bu.s[6]=f2b(v1.z); bu.s[7]=f2b(v1.w);
      tf[t] = bu.v;
    }
  }
  __syncthreads();

  f32x4 acc[16] = {};
#pragma unroll
  for (int kc = 0; kc < 8; ++kc) {
#pragma unroll
    for (int nd = 0; nd < 16; ++nd) {
      if (nd >= nd0) {
        bf16x8 afrag = *(const bf16x8*)&Ws[nd * 16 + li][kc * 32 + g * 8];
        acc[nd] = __builtin_amdgcn_mfma_f32_16x16x32_bf16(afrag, tf[kc], acc[nd], 0, 0, 0);
      }
    }
  }

#pragma unroll
  for (int nd = 0; nd < 16; ++nd) {
    if (nd < nd0) continue;
    int ncol = nd * 16 + 4 * g;
    float fv[4];
    u16 pk[4];
#pragma unroll
    for (int r = 0; r < 4; ++r) {
      int n = ncol + r;
      float bias = (n < 128) ? b_ge[n] : bc[n - 128];
      fv[r] = acc[nd][r] + bias;
      pk[r] = f2b(fv[r]);
    }
    u16* dst = (ncol < 128) ? &EA[row * 128 + ncol]
                            : &TH[row * 128 + (ncol - 128)];
    *(uint2*)dst = *(uint2*)pk;

    if (nd >= 8 && doTail) {               // tail contribution (uniform branch)
      float tv[4];
#pragma unroll
      for (int r = 0; r < 4; ++r) tv[r] = (rw >= len) ? fv[r] : 0.f;
#pragma unroll
      for (int d = 1; d < 16; d <<= 1)
#pragma unroll
        for (int r = 0; r < 4; ++r) tv[r] += __shfl_xor(tv[r], d, 16);
      if (li == 0) {
#pragma unroll
        for (int r = 0; r < 4; ++r)
          atomicAdd(&tailLds[(nd - 8) * 16 + 4 * g + r], tv[r]);
      }
    }
  }
  __syncthreads();
  if (tid < 128) {
    float v = tailLds[tid];
    if (v != 0.f) atomicAdd(&TT[b * 128 + tid], v);
  }
}

// ---------------------------------------------------------------------------
// k_attn: flash attention + masked-column tail + layernorm + row mask.
// Block = 32 q rows, 4 waves: wave = (h = row-half, p = j-parity).
// Parity p handles j-tiles 2k+p with private (m,l,O); merged at the end
// (m/l in f32, O partials via bf16 LDS). Double-buffered K/V per parity;
// next tile's global loads issued in regs before the single barrier/tile.
// K: XOR-swizzled rows. V: subtiled [8][32 j][16 d] for ds_read_b64_tr_b16.
// All LDS typed, disjoint. 75.6 KB -> 2 blocks/CU.
// ---------------------------------------------------------------------------
#define PSTR 40

__global__ __launch_bounds__(256) void k_attn(
    const u16* __restrict__ EA, const u16* __restrict__ TH,
    const float* __restrict__ TT, const int* __restrict__ lens,
    const float* __restrict__ gamma, const float* __restrict__ beta,
    float* __restrict__ out) {
  const int b  = blockIdx.y;
  const int i0 = blockIdx.x * 32;
  const int len = lens[b];
  const int tid = threadIdx.x;
  const size_t obase = ((size_t)b * L_ + i0) * 128;

  if (i0 >= len) {                         // fully masked tile -> zeros
    float4 z = {0.f, 0.f, 0.f, 0.f};
    for (int q = tid; q < 1024; q += 256) *(float4*)&out[obase + (size_t)q * 4] = z;
    return;
  }

  __shared__ u16 Kl[2][2][4096];           // [p][buf][swizzled 32x128]
  __shared__ u16 Vl[2][2][4096];           // [p][buf][t8*512 + j*16 + d%16]
  __shared__ u16 Pl[4][640];               // per-wave P tile (PSTR=40)
  __shared__ float MLm[32], MLl[32];
  __shared__ u16 MGb[32][136];             // p=1 O partials (bf16)

  const int wv = tid >> 6;
  const int h = wv & 1, p = wv >> 1;
  const int ln = tid & 63, li = ln & 15, g = ln >> 4;
  const int ptid = tid & 127;              // waves {2p,2p+1} contiguous
  const int jr = ptid >> 2, ch = ptid & 3;
  const size_t ebase = (size_t)b * L_ * 128;

  u16* pl = Pl[wv];

  // Q fragments (rows i0 + h*16 + li), hoisted
  bf16x8 qf[4];
  {
    const u16* qp = &EA[ebase + (size_t)(i0 + h * 16 + li) * 128 + g * 8];
#pragma unroll
    for (int kc = 0; kc < 4; ++kc) qf[kc] = *(const bf16x8*)&qp[kc * 32];
  }

  f32x4 Oa[8] = {};
  float m[4] = {0.f, 0.f, 0.f, 0.f};
  float lsum[4] = {0.f, 0.f, 0.f, 0.f};

  const int njt = (len + 31) >> 5;
  const int kiter = (njt + 1) >> 1;

  // prologue: issue loads for this parity's first tile
  bf16x8 kreg[4], vreg[4];
  {
    const int t0 = (p < njt) ? p : (njt - 1);
    const u16* ks = &EA[ebase + (size_t)(t0 * 32 + jr) * 128];
    const u16* vs = &TH[ebase + (size_t)(t0 * 32 + jr) * 128];
#pragma unroll
    for (int k = 0; k < 4; ++k) {
      kreg[k] = *(const bf16x8*)(ks + (ch + 4 * k) * 8);
      vreg[k] = *(const bf16x8*)(vs + (ch + 4 * k) * 8);
    }
  }

  for (int kk = 0; kk < kiter; ++kk) {
    const int t = 2 * kk + p;
    u16* kd = Kl[p][kk & 1];
    u16* vd = Vl[p][kk & 1];
    // write staged regs to LDS (b128 only)
#pragma unroll
    for (int k = 0; k < 4; ++k) {
      int cq = ch + 4 * k;
      int cb = cq * 16;
      *(bf16x8*)((char*)kd + jr * 256 + (cb ^ ((jr & 7) << 4))) = kreg[k];
      *(bf16x8*)&vd[(cq >> 1) * 512 + jr * 16 + (cq & 1) * 8] = vreg[k];
    }
    // issue next tile's loads (land during this tile's compute)
    if (kk + 1 < kiter) {
      int tn = 2 * (kk + 1) + p; if (tn > njt - 1) tn = njt - 1;
      const u16* ks = &EA[ebase + (size_t)(tn * 32 + jr) * 128];
      const u16* vs = &TH[ebase + (size_t)(tn * 32 + jr) * 128];
#pragma unroll
      for (int k = 0; k < 4; ++k) {
        kreg[k] = *(const bf16x8*)(ks + (ch + 4 * k) * 8);
        vreg[k] = *(const bf16x8*)(vs + (ch + 4 * k) * 8);
      }
    }
    __syncthreads();
    if (t < njt) {
      const int j0 = t * 32;
      // QK^T
      f32x4 S[2] = {};
#pragma unroll
      for (int n = 0; n < 2; ++n) {
        int krow = n * 16 + li;
        const char* kb = (const char*)kd + krow * 256;
#pragma unroll
        for (int kc = 0; kc < 4; ++kc) {
          bf16x8 kf = *(const bf16x8*)(kb + ((kc * 64 + g * 16) ^ ((krow & 7) << 4)));
          S[n] = __builtin_amdgcn_mfma_f32_16x16x32_bf16(qf[kc], kf, S[n], 0, 0, 0);
        }
      }
      // V transpose-reads (overlap with softmax VALU)
      const unsigned vtr = (unsigned)(size_t)vd + g * 256 + li * 8;
      uint2 vr[16];
#pragma unroll
      for (int t8 = 0; t8 < 8; ++t8) {
        unsigned a = vtr + t8 * 1024;
        TR16_0(vr[2 * t8], a);
        TR16_128(vr[2 * t8 + 1], a);
      }
      // relu + in-tile mask + online softmax
      const bool v0 = (j0 + li) < len;
      const bool v1 = (j0 + 16 + li) < len;
      float x[4];
#pragma unroll
      for (int r = 0; r < 4; ++r) {
        float s0 = v0 ? fmaxf(S[0][r], 0.f) : 0.f;
        float s1 = v1 ? fmaxf(S[1][r], 0.f) : 0.f;
        S[0][r] = s0; S[1][r] = s1;
        x[r] = fmaxf(s0, s1);
      }
#pragma unroll
      for (int d = 1; d < 16; d <<= 1)
#pragma unroll
        for (int r = 0; r < 4; ++r) x[r] = fmaxf(x[r], __shfl_xor(x[r], d, 16));

      float p0[4], p1[4], fac[4], y[4];
#pragma unroll
      for (int r = 0; r < 4; ++r) {
        float mt = fmaxf(m[r], x[r]);
        fac[r] = __expf(m[r] - mt);
        m[r] = mt;
        p0[r] = v0 ? __expf(S[0][r] - mt) : 0.f;
        p1[r] = v1 ? __expf(S[1][r] - mt) : 0.f;
        y[r] = p0[r] + p1[r];
      }
#pragma unroll
      for (int d = 1; d < 16; d <<= 1)
#pragma unroll
        for (int r = 0; r < 4; ++r) y[r] += __shfl_xor(y[r], d, 16);
#pragma unroll
      for (int r = 0; r < 4; ++r) lsum[r] = lsum[r] * fac[r] + y[r];
#pragma unroll
      for (int t8 = 0; t8 < 8; ++t8)
#pragma unroll
        for (int r = 0; r < 4; ++r) Oa[t8][r] *= fac[r];

      // P -> per-wave LDS, read back as A-fragment
#pragma unroll
      for (int r = 0; r < 4; ++r) {
        pl[(4 * g + r) * PSTR + li]      = f2b(p0[r]);
        pl[(4 * g + r) * PSTR + 16 + li] = f2b(p1[r]);
      }
      bf16x8 pf = *(const bf16x8*)&pl[li * PSTR + g * 8];

      asm volatile("s_waitcnt lgkmcnt(0)" ::: "memory");
      __builtin_amdgcn_sched_barrier(0);

#pragma unroll
      for (int t8 = 0; t8 < 8; ++t8) {
        VU vu; vu.p[0] = vr[2 * t8]; vu.p[1] = vr[2 * t8 + 1];
        Oa[t8] = __builtin_amdgcn_mfma_f32_16x16x32_bf16(pf, vu.v, Oa[t8], 0, 0, 0);
      }
    }
  }

  // ---- merge parity partials ----
  __syncthreads();
  if (p == 1) {
#pragma unroll
    for (int r = 0; r < 4; ++r) {
      int rr = h * 16 + 4 * g + r;
      if (li == 0) { MLm[rr] = m[r]; MLl[rr] = lsum[r]; }
#pragma unroll
      for (int t8 = 0; t8 < 8; ++t8)
        MGb[rr][t8 * 16 + li] = f2b(Oa[t8][r]);
    }
  }
  __syncthreads();
  if (p != 0) return;

#pragma unroll
  for (int r = 0; r < 4; ++r) {
    int rr = h * 16 + 4 * g + r;
    float m1 = MLm[rr], l1 = MLl[rr];
    float ms = fmaxf(m[r], m1);
    float f0 = __expf(m[r] - ms), f1 = __expf(m1 - ms);
    lsum[r] = lsum[r] * f0 + l1 * f1;
    m[r] = ms;
#pragma unroll
    for (int t8 = 0; t8 < 8; ++t8)
      Oa[t8][r] = Oa[t8][r] * f0 + b2f(MGb[rr][t8 * 16 + li]) * f1;
  }

  // masked-column tail: (L-len) cols with score 0 -> weight e^{-m}
  {
    float tt8[8];
#pragma unroll
    for (int t8 = 0; t8 < 8; ++t8) tt8[t8] = TT[b * 128 + t8 * 16 + li];
#pragma unroll
    for (int r = 0; r < 4; ++r) {
      float wt = __expf(-m[r]);
      lsum[r] += wt * (float)(L_ - len);
#pragma unroll
      for (int t8 = 0; t8 < 8; ++t8) Oa[t8][r] += wt * tt8[t8];
    }
  }

  // normalize + layernorm
  float sm[4] = {0.f, 0.f, 0.f, 0.f}, sq[4] = {0.f, 0.f, 0.f, 0.f};
#pragma unroll
  for (int r = 0; r < 4; ++r) {
    float inv = 1.f / lsum[r];
#pragma unroll
    for (int t8 = 0; t8 < 8; ++t8) {
      float val = Oa[t8][r] * inv;
      Oa[t8][r] = val;
      sm[r] += val; sq[r] += val * val;
    }
  }
#pragma unroll
  for (int d = 1; d < 16; d <<= 1)
#pragma unroll
    for (int r = 0; r < 4; ++r) {
      sm[r] += __shfl_xor(sm[r], d, 16);
      sq[r] += __shfl_xor(sq[r], d, 16);
    }

  const int irow = i0 + h * 16;
#pragma unroll
  for (int r = 0; r < 4; ++r) {
    float mu   = sm[r] * (1.f / 128.f);
    float var  = sq[r] * (1.f / 128.f) - mu * mu;
    float rstd = rsqrtf(var + 1e-5f);
    int i = irow + 4 * g + r;
    bool valid = i < len;
#pragma unroll
    for (int t8 = 0; t8 < 8; ++t8) {
      int dcol = t8 * 16 + li;
      float o = valid ? ((Oa[t8][r] - mu) * rstd * gamma[dcol] + beta[dcol]) : 0.f;
      out[((size_t)b * L_ + i) * 128 + dcol] = o;
    }
  }
}

// ---------------------------------------------------------------------------
extern "C" void kernel_launch(void* const* d_in, const int* in_sizes, int n_in,
                              void* d_out, int out_size, void* d_ws, size_t ws_size,
                              hipStream_t stream) {
  const float* traj  = (const float*)d_in[0];
  const int*   lens  = (const int*)d_in[1];
  const float* W_ge  = (const float*)d_in[2];
  const float* b_ge  = (const float*)d_in[3];
  const float* W_eg  = (const float*)d_in[4];
  const float* b_eg  = (const float*)d_in[5];
  const float* Wg    = (const float*)d_in[6];
  const float* gamma = (const float*)d_in[7];
  const float* beta  = (const float*)d_in[8];
  float* out = (float*)d_out;

  // workspace: WbT bf16[256*256] | bc f32[128] | TT f32[32*128] | EA bf16 | TH bf16
  char* ws = (char*)d_ws;
  u16*   WbT = (u16*)ws;
  float* bc  = (float*)(ws + 131072);
  float* TT  = (float*)(ws + 131072 + 512);
  u16*   EA  = (u16*)(ws + 131072 + 512 + 16384);
  u16*   TH  = EA + (size_t)B_ * L_ * 128;

  k_fold<<<273, 256, 0, stream>>>(W_ge, b_eg, W_eg, Wg, WbT, bc, TT);
  k_embed<<<256, 512, 0, stream>>>(traj, WbT, b_ge, bc, lens, EA, TH, TT);
  k_attn<<<dim3(32, 32), 256, 0, stream>>>(EA, TH, TT, lens, gamma, beta, out);
}